// Round 10
// baseline (580.295 us; speedup 1.0000x reference)
//
#include <hip/hip_runtime.h>
#include <hip/hip_bf16.h>

typedef __attribute__((ext_vector_type(8))) short short8;
typedef __attribute__((ext_vector_type(4))) float f32x4;

#define NTOP 1000
#define KC   256
#define MROWS 40000

static __device__ __forceinline__ unsigned short f2bf(float x) {
    union { float f; unsigned u; } v; v.f = x;
    unsigned r = (v.u + 0x7FFFu + ((v.u >> 16) & 1u)) >> 16;
    return (unsigned short)r;
}

static __device__ __forceinline__ void gl16(const void* src, void* dst) {
    __builtin_amdgcn_global_load_lds(
        (const __attribute__((address_space(1))) unsigned int*)src,
        (__attribute__((address_space(3))) unsigned int*)dst, 16, 0, 0);
}

// Kernel 1: colsum[j] += sum over an 8-row slab of nw. colsum pre-zeroed by memset.
__global__ void k_prep(const float* __restrict__ nw,
                       float* __restrict__ colsum) {
    int j  = blockIdx.x * 256 + threadIdx.x;
    int i0 = blockIdx.y * 8;
    if (j < NTOP) {
        float s = 0.f;
        int iend = min(i0 + 8, NTOP);
        for (int i = i0; i < iend; ++i) s += nw[(size_t)i * NTOP + j];
        atomicAdd(colsum + j, s);
    }
}

// Kernel 2: build B' (V_j) in MFMA-fragment order:
//   B'[((nt*8 + s)*64 + lane)] (short8) = V_j[n = nt*16 + (lane&15),
//                                             k = s*32 + (lane>>4)*8 + j]
__global__ void k_vj(const float* __restrict__ V,
                     const float* __restrict__ noise,
                     const float* __restrict__ colsum,
                     unsigned short* __restrict__ Bp) {
    int t  = blockIdx.x * 256 + threadIdx.x;   // 0 .. 32767
    int nt = t >> 9;
    int s  = (t >> 6) & 7;
    int l  = t & 63;
    int lm = l & 15, lq = l >> 4;
    int n  = nt * 16 + lm;
    int k0 = s * 32 + lq * 8;
    union { short8 v; unsigned short us[8]; } pk;
    if (n < NTOP) {
        float cs = colsum[n];
        #pragma unroll
        for (int j = 0; j < 8; ++j) {
            int idx = n * KC + k0 + j;
            pk.us[j] = f2bf(V[idx] * cs + 0.1f * noise[idx]);
        }
    } else {
        #pragma unroll
        for (int j = 0; j < 8; ++j) pk.us[j] = 0;
    }
    reinterpret_cast<short8*>(Bp)[t] = pk.v;
}

// Kernel 2c: U_emb precompute. Streams U (205 MB) fully coalesced and writes
// U_emb as bf16 in MFMA A-fragment order (20.5 MB):
//   Af[(mt*8+s)*64 + lane] = emb[m = mt*16+(lane&15)][k = s*32+(lane>>4)*8+j]
__global__ __launch_bounds__(256) void k_emb(const float* __restrict__ U,
                                             const float* __restrict__ w5,
                                             const float* __restrict__ b1,
                                             unsigned short* __restrict__ Af) {
    __shared__ float emb[16][257];
    const int tid  = threadIdx.x;
    const int wave = tid >> 6;
    const int l    = tid & 63;
    const int mt   = blockIdx.x;

    const float w0 = w5[0], w1 = w5[1], w2 = w5[2], w3 = w5[3], w4 = w5[4];
    const float bb = b1[0];

    #pragma unroll
    for (int p = 0; p < 4; ++p) {
        const int r = p * 4 + wave;
        const float4* up = reinterpret_cast<const float4*>(
            U + (size_t)(mt * 16 + r) * (KC * 5) + l * 20);
        float f[20];
        #pragma unroll
        for (int i = 0; i < 5; ++i) {
            float4 t4 = up[i];
            f[i*4+0] = t4.x; f[i*4+1] = t4.y; f[i*4+2] = t4.z; f[i*4+3] = t4.w;
        }
        #pragma unroll
        for (int q = 0; q < 4; ++q) {
            const float* ff = f + q * 5;
            emb[r][l * 4 + q] = ff[0]*w0 + ff[1]*w1 + ff[2]*w2 + ff[3]*w3
                              + ff[4]*w4 + bb;
        }
    }
    __syncthreads();

    const int lm = l & 15, lq = l >> 4;
    #pragma unroll
    for (int g = 0; g < 2; ++g) {
        const int s  = wave + g * 4;
        const int k0 = s * 32 + lq * 8;
        union { short8 v; unsigned short us[8]; } pk;
        #pragma unroll
        for (int j = 0; j < 8; ++j) pk.us[j] = f2bf(emb[lm][k0 + j]);
        reinterpret_cast<short8*>(Af)[(mt * 8 + s) * 64 + l] = pk.v;
    }
}

// ---------------- k_main v11: independent waves, 0 LDS, 0 barriers ----------------
// Grid 625 x 256thr; wave owns mt = blockIdx*4 + wave (16 rows, all 1000 cols).
// 64 n-tiles, unrolled x2 with NAMED register sets (rule #20: static indexing):
//   issue loads(set B, nt+1) -> MFMA+epilogue(set A, nt) -> issue loads(set A,
//   nt+2) -> MFMA+epilogue(set B, nt+1).
// Every load covered by a half-iteration of compute; compiler emits counted
// vmcnt; waves drift independently -> cross-wave pipe overlap (no lockstep).
// launch_bounds(256,3): ~170 VGPR cap for ~140 live; 12 waves/CU, grid fully
// co-resident (625 blocks <= 256 CU x 3), no residency tail.
__global__ __launch_bounds__(256, 3) void k_main(
    const short8* __restrict__ Af, const short8* __restrict__ Bf,
    const float* __restrict__ R, const int* __restrict__ C,
    float* __restrict__ out)
{
    const int tid  = threadIdx.x;
    const int wave = tid >> 6;
    const int l    = tid & 63;
    const int lm = l & 15;
    const int lq = l >> 4;
    const int mt = blockIdx.x * 4 + wave;
    const int m  = mt * 16 + lm;
    const size_t rowbase = (size_t)m * NTOP;

    // A-fragments for this wave's 16 rows (8 coalesced 1 KB loads)
    short8 afr[8];
    #pragma unroll
    for (int s = 0; s < 8; ++s) afr[s] = Af[((mt * 8 + s) << 6) + l];

    float lpsum = 0.f;

    // ---- software pipeline: named sets A (even nt) / B (odd nt) ----
    short8 bA[8], bB[8];
    float4 rA, rB; int4 cA, cB;

    // preload set A for nt=0
    #pragma unroll
    for (int s = 0; s < 8; ++s) bA[s] = Bf[(s << 6) + l];
    {
        const int nb = lq * 4;   // nt=0: always in bounds
        rA = *reinterpret_cast<const float4*>(R + rowbase + nb);
        cA = *reinterpret_cast<const int4*>(C + rowbase + nb);
    }

    for (int nt = 0; nt < 64; nt += 2) {
        // issue set-B loads for nt+1 (covered by compute on set A)
        #pragma unroll
        for (int s = 0; s < 8; ++s) bB[s] = Bf[(((nt + 1) * 8 + s) << 6) + l];
        {
            int nb = (nt + 1) * 16 + lq * 4;
            nb = nb < 996 ? nb : 996;
            rB = *reinterpret_cast<const float4*>(R + rowbase + nb);
            cB = *reinterpret_cast<const int4*>(C + rowbase + nb);
        }

        // compute nt on set A
        {
            f32x4 acc = (f32x4){0.f, 0.f, 0.f, 0.f};
            #pragma unroll
            for (int s = 0; s < 8; ++s)
                acc = __builtin_amdgcn_mfma_f32_16x16x32_bf16(bA[s], afr[s], acc, 0, 0, 0);
            const float* rp = reinterpret_cast<const float*>(&rA);
            const int*   cp = reinterpret_cast<const int*>(&cA);
            #pragma unroll
            for (int r = 0; r < 4; ++r) {
                const int n = nt * 16 + lq * 4 + r;
                float x   = acc[r];
                float muv = 1.f / (1.f + __expf(-x));
                float d   = rp[r] - muv;
                float lp  = -50.f * d * d + 1.3836465597893728f;
                if (cp[r] == 1 && n < NTOP) lpsum += lp;
            }
        }

        // issue set-A loads for nt+2 (covered by compute on set B)
        if (nt + 2 < 64) {
            #pragma unroll
            for (int s = 0; s < 8; ++s) bA[s] = Bf[(((nt + 2) * 8 + s) << 6) + l];
            int nb = (nt + 2) * 16 + lq * 4;
            nb = nb < 996 ? nb : 996;
            rA = *reinterpret_cast<const float4*>(R + rowbase + nb);
            cA = *reinterpret_cast<const int4*>(C + rowbase + nb);
        }

        // compute nt+1 on set B
        {
            f32x4 acc = (f32x4){0.f, 0.f, 0.f, 0.f};
            #pragma unroll
            for (int s = 0; s < 8; ++s)
                acc = __builtin_amdgcn_mfma_f32_16x16x32_bf16(bB[s], afr[s], acc, 0, 0, 0);
            const float* rp = reinterpret_cast<const float*>(&rB);
            const int*   cp = reinterpret_cast<const int*>(&cB);
            #pragma unroll
            for (int r = 0; r < 4; ++r) {
                const int n = (nt + 1) * 16 + lq * 4 + r;
                float x   = acc[r];
                float muv = 1.f / (1.f + __expf(-x));
                float d   = rp[r] - muv;
                float lp  = -50.f * d * d + 1.3836465597893728f;
                if (cp[r] == 1 && n < NTOP) lpsum += lp;
            }
        }
    }

    #pragma unroll
    for (int off = 32; off > 0; off >>= 1) lpsum += __shfl_down(lpsum, off);
    if (l == 0) atomicAdd(out, lpsum);
}

// ---------------- fallback if workspace too small (v10 fb, proven) ----------------
__global__ __launch_bounds__(256, 4) void k_main_fb(
    const float* __restrict__ U, const float* __restrict__ w5,
    const float* __restrict__ b1, const short8* __restrict__ Bf,
    const float* __restrict__ R, const int* __restrict__ C,
    float* __restrict__ out)
{
    __shared__ short8 BfL[2][1024];

    const int tid  = threadIdx.x;
    const int wave = tid >> 6;
    const int l    = tid & 63;
    const int lm = l & 15;
    const int lq = l >> 4;
    const int wr = wave >> 1;
    const int wc = wave & 1;
    const int mt = blockIdx.x * 2 + wr;
    const int m  = mt * 16 + lm;

    auto stageBf = [&](int buf, int hs) {
        const char* src = (const char*)Bf + ((size_t)hs << 14) + (size_t)tid * 16;
        char*       dst = (char*)&BfL[buf][0] + (size_t)tid * 16;
        #pragma unroll
        for (int i = 0; i < 4; ++i) gl16(src + i * 4096, dst + i * 4096);
    };

    stageBf(0, 0);
    const float w0 = w5[0], w1 = w5[1], w2 = w5[2], w3 = w5[3], w4 = w5[4];
    const float bb = b1[0];
    short8 afr[8];
    #pragma unroll
    for (int s = 0; s < 8; ++s) {
        const float4* up4 = reinterpret_cast<const float4*>(
            U + (size_t)(m * KC + s * 32 + lq * 8) * 5);
        float u[40];
        #pragma unroll
        for (int i = 0; i < 10; ++i) {
            float4 t4 = up4[i];
            u[i*4+0] = t4.x; u[i*4+1] = t4.y; u[i*4+2] = t4.z; u[i*4+3] = t4.w;
        }
        union { short8 v; unsigned short us[8]; } pk;
        #pragma unroll
        for (int j = 0; j < 8; ++j) {
            const float* uu = u + j * 5;
            pk.us[j] = f2bf(uu[0]*w0 + uu[1]*w1 + uu[2]*w2 + uu[3]*w3 + uu[4]*w4 + bb);
        }
        afr[s] = pk.v;
    }

    const size_t rowbase = (size_t)m * NTOP;
    float4 r4c = *reinterpret_cast<const float4*>(R + rowbase + wc * 16 + lq * 4);
    int4   c4c = *reinterpret_cast<const int4*>(C + rowbase + wc * 16 + lq * 4);

    asm volatile("s_waitcnt vmcnt(2)" ::: "memory");
    __builtin_amdgcn_s_barrier();

    float lpsum = 0.f;
    for (int hs = 0; hs < 32; ++hs) {
        const int cur = hs & 1;
        if (hs < 31) stageBf(cur ^ 1, hs + 1);
        __builtin_amdgcn_sched_barrier(0);
        float4 r4n = r4c; int4 c4n = c4c;
        if (hs < 31) {
            int nb = (hs + 1) * 32 + wc * 16 + lq * 4;
            nb = nb < 996 ? nb : 996;
            r4n = *reinterpret_cast<const float4*>(R + rowbase + nb);
            c4n = *reinterpret_cast<const int4*>(C + rowbase + nb);
        }
        f32x4 acc = (f32x4){0.f, 0.f, 0.f, 0.f};
        #pragma unroll
        for (int s = 0; s < 8; ++s) {
            const short8 bfr = BfL[cur][((wc * 8 + s) << 6) + l];
            acc = __builtin_amdgcn_mfma_f32_16x16x32_bf16(bfr, afr[s], acc, 0, 0, 0);
        }
        const float* rp = reinterpret_cast<const float*>(&r4c);
        const int*   cp = reinterpret_cast<const int*>(&c4c);
        #pragma unroll
        for (int r = 0; r < 4; ++r) {
            const int n = hs * 32 + wc * 16 + lq * 4 + r;
            float x   = acc[r];
            float muv = 1.f / (1.f + __expf(-x));
            float d   = rp[r] - muv;
            float lp  = -50.f * d * d + 1.3836465597893728f;
            if (cp[r] == 1 && n < NTOP) lpsum += lp;
        }
        if (hs < 31) {
            asm volatile("s_waitcnt vmcnt(2)" ::: "memory");
            __builtin_amdgcn_s_barrier();
        }
        r4c = r4n; c4c = c4n;
    }

    #pragma unroll
    for (int off = 32; off > 0; off >>= 1) lpsum += __shfl_down(lpsum, off);
    if (l == 0) atomicAdd(out, lpsum);
}

extern "C" void kernel_launch(void* const* d_in, const int* in_sizes, int n_in,
                              void* d_out, int out_size, void* d_ws, size_t ws_size,
                              hipStream_t stream) {
    const float* V     = (const float*)d_in[1];
    const float* R     = (const float*)d_in[2];
    const float* nw    = (const float*)d_in[3];
    const float* U     = (const float*)d_in[4];
    const float* w5    = (const float*)d_in[5];
    const float* b1    = (const float*)d_in[6];
    const float* noise = (const float*)d_in[7];
    const int*   C     = (const int*)d_in[8];
    float* out = (float*)d_out;

    float* colsum       = (float*)d_ws;
    unsigned short* Bp  = (unsigned short*)((char*)d_ws + 8192);
    unsigned short* Afp = (unsigned short*)((char*)d_ws + 8192 + 524288);
    const size_t ws_needed = 8192 + 524288 + (size_t)2500 * 8 * 64 * 16;

    hipMemsetAsync(colsum, 0, NTOP * sizeof(float), stream);
    hipMemsetAsync(out, 0, sizeof(float), stream);
    hipLaunchKernelGGL(k_prep, dim3(4, 125), dim3(256), 0, stream, nw, colsum);
    hipLaunchKernelGGL(k_vj, dim3(128), dim3(256), 0, stream,
                       V, noise, colsum, Bp);

    if (ws_size >= ws_needed) {
        hipLaunchKernelGGL(k_emb, dim3(2500), dim3(256), 0, stream,
                           U, w5, b1, Afp);
        hipLaunchKernelGGL(k_main, dim3(625), dim3(256), 0, stream,
                           (const short8*)Afp, (const short8*)Bp, R, C, out);
    } else {
        hipLaunchKernelGGL(k_main_fb, dim3(1250), dim3(256), 0, stream,
                           U, w5, b1, (const short8*)Bp, R, C, out);
    }
}